// Round 5
// baseline (367.426 us; speedup 1.0000x reference)
//
#include <hip/hip_runtime.h>
#include <math.h>

#define N_C 1024
#define M_F 64
#define B_R 32768
#define R_B 32       // sample rows per block (2 m-tiles of 16)
#define LDX 132      // padded fp32 leading dim for X in LDS

typedef short bf16x8 __attribute__((ext_vector_type(8)));
typedef float f32x4 __attribute__((ext_vector_type(4)));
typedef unsigned int uint4v __attribute__((ext_vector_type(4)));

__device__ __forceinline__ short f2bf(float x) {
  unsigned b = __float_as_uint(x);
  b += 0x7fffu + ((b >> 16) & 1u);   // RTNE (finite inputs only)
  return (short)(b >> 16);
}
__device__ __forceinline__ float bf2f(short h) {
  return __uint_as_float(((unsigned)(unsigned short)h) << 16);
}

// Exact truncation-based 3-way split (h+m+l == x exactly); bit-ops only.
__device__ __forceinline__ void split3(const float* f, bf16x8& h, bf16x8& m, bf16x8& l) {
  uint4v hp, mp, lp;
#pragma unroll
  for (int i = 0; i < 4; ++i) {
    const unsigned b0 = __float_as_uint(f[2 * i]);
    const unsigned b1 = __float_as_uint(f[2 * i + 1]);
    const unsigned h0 = b0 & 0xFFFF0000u, h1 = b1 & 0xFFFF0000u;
    const float r0 = f[2 * i] - __uint_as_float(h0);       // exact
    const float r1 = f[2 * i + 1] - __uint_as_float(h1);   // exact
    hp[i] = (b0 >> 16) | h1;
    const unsigned rb0 = __float_as_uint(r0), rb1 = __float_as_uint(r1);
    const unsigned m0 = rb0 & 0xFFFF0000u, m1 = rb1 & 0xFFFF0000u;
    const float s0 = r0 - __uint_as_float(m0);             // exact
    const float s1 = r1 - __uint_as_float(m1);             // exact
    mp[i] = (rb0 >> 16) | m1;
    lp[i] = (__float_as_uint(s0) >> 16) | (__float_as_uint(s1) & 0xFFFF0000u);
  }
  h = __builtin_bit_cast(bf16x8, hp);
  m = __builtin_bit_cast(bf16x8, mp);
  l = __builtin_bit_cast(bf16x8, lp);
}

// Merged prep: blocks 0..63 build the exact 3-way bf16 split of Y = [C | C^2]
// (MFMA B-frag swizzled); block 64 computes log_softmax(log_marginal).
// Y blob[(s*64 + c)*64 + lane] holds Y[n = c*16+(lane&15)][k = s*32+(lane>>4)*8 ..+7]
__global__ void prep(const float* __restrict__ centroids,
                     const float* __restrict__ lm,
                     bf16x8* __restrict__ yh, bf16x8* __restrict__ ym,
                     bf16x8* __restrict__ yl, float* __restrict__ lp) {
  __shared__ float red[256];
  const int t = threadIdx.x;

  if (blockIdx.x == 64) {
    // ---- log-prior: log_softmax over 1024 entries ----
    float v[4];
    float mx = -INFINITY;
#pragma unroll
    for (int i = 0; i < 4; ++i) { v[i] = lm[i * 256 + t]; mx = fmaxf(mx, v[i]); }
    red[t] = mx;
    __syncthreads();
    for (int s = 128; s > 0; s >>= 1) {
      if (t < s) red[t] = fmaxf(red[t], red[t + s]);
      __syncthreads();
    }
    mx = red[0];
    __syncthreads();
    float sum = 0.f;
#pragma unroll
    for (int i = 0; i < 4; ++i) { v[i] -= mx; sum += expf(v[i]); }
    red[t] = sum;
    __syncthreads();
    for (int s = 128; s > 0; s >>= 1) {
      if (t < s) red[t] += red[t + s];
      __syncthreads();
    }
    const float l = logf(red[0]);
#pragma unroll
    for (int i = 0; i < 4; ++i) lp[i * 256 + t] = v[i] - l;
    return;
  }

  // ---- Y prep ----
  const int tid = blockIdx.x * 256 + t;  // 0..16383
  const int l = tid & 63;
  const int c = (tid >> 6) & 63;
  const int s = tid >> 12;
  const int n = c * 16 + (l & 15);
  const int k0 = s * 32 + (l >> 4) * 8;
  bf16x8 h, mid, lo;
#pragma unroll
  for (int j = 0; j < 8; ++j) {
    const int k = k0 + j;
    float y;
    if (k < 64) {
      y = centroids[n * M_F + k];
    } else {
      const float cc = centroids[n * M_F + (k - 64)];
      y = cc * cc;
    }
    const short hh = f2bf(y);
    const float r1 = y - bf2f(hh);        // exact
    const short mm = f2bf(r1);
    const float r2 = r1 - bf2f(mm);       // exact
    h[j] = hh;
    mid[j] = mm;
    lo[j] = f2bf(r2);                     // exact
  }
  const int blob = (s * 64 + c) * 64 + l;
  yh[blob] = h;
  ym[blob] = mid;
  yl[blob] = lo;
}

// 256 threads = 4 waves. Wave w: c-tiles w*16..w*16+15 (cols w*256..+255),
// 2 m-tiles (rows 0-15, 16-31). 1024 blocks, 2 waves/SIMD.
// Output stores are NON-TEMPORAL: the 268 MB store stream must not allocate
// in L2, which would thrash the L2-resident Y operand (2.3 MB/XCD) and turn
// Y re-reads into HBM misses. Values stored are bit-identical.
__global__ __launch_bounds__(256, 2) void rmm_main(
    const float* __restrict__ samples, const float* __restrict__ mask,
    const float* __restrict__ sd, const float* __restrict__ lp_g,
    const bf16x8* __restrict__ yh_g, const bf16x8* __restrict__ ym_g,
    const bf16x8* __restrict__ yl_g, float* __restrict__ out) {
  __shared__ float xs[R_B * LDX];   // X fp32 [row][k]: k<64 -> -2uA, k>=64 -> u
  __shared__ float lp_s[N_C];
  __shared__ float ad_s[R_B];
  __shared__ float red_s[R_B * 4];

  const int t = threadIdx.x;
  const int b0 = blockIdx.x * R_B;
  const int w = t >> 6;
  const int l = t & 63;
  const int m = l & 15;
  const int q = l >> 4;

  *(float4*)(lp_s + (t << 2)) = *(const float4*)(lp_g + (t << 2));

  // Prefill B pairs 0,1 (tiles 0..3 of s=0): latency hides under X-build.
  const size_t base0 = (size_t)(w * 16) * 64 + l;
  bf16x8 Bh[2][2], Bm[2][2], Bl[2][2];   // [pair-slot][elem]
#pragma unroll
  for (int p = 0; p < 2; ++p)
#pragma unroll
    for (int e = 0; e < 2; ++e) {
      Bh[p][e] = yh_g[base0 + (p * 2 + e) * 64];
      Bm[p][e] = ym_g[base0 + (p * 2 + e) * 64];
      Bl[p][e] = yl_g[base0 + (p * 2 + e) * 64];
    }

  // ---- build X rows, A_d: 256 thr = 32 rows x 8 lanes x 8 features ----
  {
    const int r = t >> 3;             // 0..31
    const int j8 = (t & 7) << 3;
    const float* sp = samples + (size_t)(b0 + r) * M_F + j8;
    const float* mp = mask + (size_t)(b0 + r) * M_F + j8;
    float sa[8], ma[8], da[8];
    *(float4*)&sa[0] = *(const float4*)sp;
    *(float4*)&sa[4] = *(const float4*)(sp + 4);
    *(float4*)&ma[0] = *(const float4*)mp;
    *(float4*)&ma[4] = *(const float4*)(mp + 4);
    *(float4*)&da[0] = *(const float4*)(sd + j8);
    *(float4*)&da[4] = *(const float4*)(sd + j8 + 4);
    float ad = 0.f;
#pragma unroll
    for (int k = 0; k < 8; ++k) {
      const float mm = ma[k] / da[k];
      const float uu = mm * mm;
      const float mA = mm * sa[k];
      ad = fmaf(mA, mA, ad);
      xs[r * LDX + j8 + k] = -2.0f * (uu * sa[k]);
      xs[r * LDX + 64 + j8 + k] = uu;
    }
#pragma unroll
    for (int off = 1; off < 8; off <<= 1) ad += __shfl_xor(ad, off, 64);
    if ((t & 7) == 0) ad_s[r] = ad;
  }

  f32x4 acc[2][16];
#pragma unroll
  for (int mt = 0; mt < 2; ++mt)
#pragma unroll
    for (int c = 0; c < 16; ++c) acc[mt][c] = (f32x4){0.f, 0.f, 0.f, 0.f};

  __syncthreads();

  // split order per accumulator (small -> large); 0=h,1=m,2=l
  const int sx[8] = {1, 2, 0, 1, 2, 0, 1, 0};
  const int sy[8] = {2, 1, 2, 1, 0, 1, 0, 0};

  // ---- K loop: 4 steps of K=32; pair-granular double-buffered prefetch,
  //      depth 2 pairs (4 tiles), carried across s ----
#pragma unroll 1
  for (int s = 0; s < 4; ++s) {
    const size_t sbase = (size_t)(s * 64 + w * 16) * 64 + l;
    const bf16x8* yh = yh_g + sbase;
    const bf16x8* ym = ym_g + sbase;
    const bf16x8* yl = yl_g + sbase;

    bf16x8 A[3][2];
#pragma unroll
    for (int mt = 0; mt < 2; ++mt) {
      const float* xp = &xs[(mt * 16 + m) * LDX + s * 32 + q * 8];
      float av[8];
      *(float4*)&av[0] = *(const float4*)xp;
      *(float4*)&av[4] = *(const float4*)(xp + 4);
      split3(av, A[0][mt], A[1][mt], A[2][mt]);
    }

#pragma unroll
    for (int cp = 0; cp < 8; ++cp) {
      const int buf = cp & 1;
      // current pair's fragments (copy before overwrite by prefetch)
      const bf16x8 bh0 = Bh[buf][0], bm0 = Bm[buf][0], bl0 = Bl[buf][0];
      const bf16x8 bh1 = Bh[buf][1], bm1 = Bm[buf][1], bl1 = Bl[buf][1];
      // prefetch pair cp+2 into this slot (pf>=16 -> next K-step's tiles)
      const int pf0 = 2 * cp + 4;
      if (s < 3 || pf0 + 1 < 16) {
        const int o0 = (pf0 < 16) ? pf0 * 64 : 4096 + (pf0 - 16) * 64;
        const int o1 = (pf0 + 1 < 16) ? (pf0 + 1) * 64 : 4096 + (pf0 - 15) * 64;
        Bh[buf][0] = yh[o0]; Bm[buf][0] = ym[o0]; Bl[buf][0] = yl[o0];
        Bh[buf][1] = yh[o1]; Bm[buf][1] = ym[o1]; Bl[buf][1] = yl[o1];
      }
      const int c0 = 2 * cp, c1 = 2 * cp + 1;
#pragma unroll
      for (int sp = 0; sp < 8; ++sp) {
        const bf16x8 b0 = (sy[sp] == 0) ? bh0 : ((sy[sp] == 1) ? bm0 : bl0);
        const bf16x8 b1 = (sy[sp] == 0) ? bh1 : ((sy[sp] == 1) ? bm1 : bl1);
        // 4 independent chains between dependent uses of the same acc
#pragma unroll
        for (int mt = 0; mt < 2; ++mt)
          acc[mt][c0] = __builtin_amdgcn_mfma_f32_16x16x32_bf16(
              A[sx[sp]][mt], b0, acc[mt][c0], 0, 0, 0);
#pragma unroll
        for (int mt = 0; mt < 2; ++mt)
          acc[mt][c1] = __builtin_amdgcn_mfma_f32_16x16x32_bf16(
              A[sx[sp]][mt], b1, acc[mt][c1], 0, 0, 0);
      }
    }
  }

  // ---- epilogue: C/D row = mt*16 + q*4+g, col = w*256 + c*16 + m ----
  float adv[2][4];
#pragma unroll
  for (int mt = 0; mt < 2; ++mt)
#pragma unroll
    for (int g = 0; g < 4; ++g) adv[mt][g] = ad_s[mt * 16 + q * 4 + g];
  float lpv[16];
#pragma unroll
  for (int c = 0; c < 16; ++c) lpv[c] = lp_s[w * 256 + c * 16 + m];

#pragma unroll
  for (int mt = 0; mt < 2; ++mt)
#pragma unroll
    for (int c = 0; c < 16; ++c)
#pragma unroll
      for (int g = 0; g < 4; ++g) {
        const float dist = fmaxf(adv[mt][g] + acc[mt][c][g], 0.0f);
        acc[mt][c][g] = lpv[c] - 0.5f * dist;
      }

  float mx[2][4];
#pragma unroll
  for (int mt = 0; mt < 2; ++mt)
#pragma unroll
    for (int g = 0; g < 4; ++g) {
      float v = acc[mt][0][g];
#pragma unroll
      for (int c = 1; c < 16; ++c) v = fmaxf(v, acc[mt][c][g]);
#pragma unroll
      for (int off = 1; off < 16; off <<= 1) v = fmaxf(v, __shfl_xor(v, off, 64));
      mx[mt][g] = v;
    }
  if (m == 0) {
#pragma unroll
    for (int mt = 0; mt < 2; ++mt)
#pragma unroll
      for (int g = 0; g < 4; ++g) red_s[(mt * 16 + q * 4 + g) * 4 + w] = mx[mt][g];
  }
  __syncthreads();
#pragma unroll
  for (int mt = 0; mt < 2; ++mt)
#pragma unroll
    for (int g = 0; g < 4; ++g) {
      const float4 rv = *(const float4*)(&red_s[(mt * 16 + q * 4 + g) * 4]);
      mx[mt][g] = fmaxf(fmaxf(rv.x, rv.y), fmaxf(rv.z, rv.w));
    }
  __syncthreads();

  float sm[2][4];
#pragma unroll
  for (int mt = 0; mt < 2; ++mt)
#pragma unroll
    for (int g = 0; g < 4; ++g) {
      float ssum = 0.f;
#pragma unroll
      for (int c = 0; c < 16; ++c) {
        const float e = __expf(acc[mt][c][g] - mx[mt][g]);
        acc[mt][c][g] = e;
        ssum += e;
      }
#pragma unroll
      for (int off = 1; off < 16; off <<= 1) ssum += __shfl_xor(ssum, off, 64);
      sm[mt][g] = ssum;
    }
  if (m == 0) {
#pragma unroll
    for (int mt = 0; mt < 2; ++mt)
#pragma unroll
      for (int g = 0; g < 4; ++g) red_s[(mt * 16 + q * 4 + g) * 4 + w] = sm[mt][g];
  }
  __syncthreads();
#pragma unroll
  for (int mt = 0; mt < 2; ++mt)
#pragma unroll
    for (int g = 0; g < 4; ++g) {
      const float4 rv = *(const float4*)(&red_s[(mt * 16 + q * 4 + g) * 4]);
      sm[mt][g] = (rv.x + rv.y) + (rv.z + rv.w);
    }
  __syncthreads();

  float thr[2][4], qs[2][4];
#pragma unroll
  for (int mt = 0; mt < 2; ++mt)
#pragma unroll
    for (int g = 0; g < 4; ++g) {
      const float S1 = sm[mt][g];
      thr[mt][g] = 0.05f * (1.0f / S1);
      float s2 = 0.f;
#pragma unroll
      for (int c = 0; c < 16; ++c) {
        const float p = acc[mt][c][g] / S1;   // IEEE div, matches np decision band
        acc[mt][c][g] = p;
        s2 += (p > thr[mt][g]) ? p : 0.0f;
      }
#pragma unroll
      for (int off = 1; off < 16; off <<= 1) s2 += __shfl_xor(s2, off, 64);
      qs[mt][g] = s2;
    }
  if (m == 0) {
#pragma unroll
    for (int mt = 0; mt < 2; ++mt)
#pragma unroll
      for (int g = 0; g < 4; ++g) red_s[(mt * 16 + q * 4 + g) * 4 + w] = qs[mt][g];
  }
  __syncthreads();
#pragma unroll
  for (int mt = 0; mt < 2; ++mt)
#pragma unroll
    for (int g = 0; g < 4; ++g) {
      const float4 rv = *(const float4*)(&red_s[(mt * 16 + q * 4 + g) * 4]);
      qs[mt][g] = (rv.x + rv.y) + (rv.z + rv.w);
    }

  const size_t colbase = (size_t)(w * 256 + m);
#pragma unroll
  for (int mt = 0; mt < 2; ++mt)
#pragma unroll
    for (int g = 0; g < 4; ++g) {
      const float rq = 1.0f / qs[mt][g];
      float* orow = out + (size_t)(b0 + mt * 16 + q * 4 + g) * N_C + colbase;
      float* lrow = orow + (size_t)B_R * N_C;
#pragma unroll
      for (int c = 0; c < 16; ++c) {
        const float p = acc[mt][c][g];
        const float pf = (p > thr[mt][g]) ? (p * rq) : 0.0f;
        __builtin_nontemporal_store(pf, orow + c * 16);
        __builtin_nontemporal_store(__logf(pf + 1e-20f), lrow + c * 16);
      }
    }
}

extern "C" void kernel_launch(void* const* d_in, const int* in_sizes, int n_in,
                              void* d_out, int out_size, void* d_ws, size_t ws_size,
                              hipStream_t stream) {
  const float* samples   = (const float*)d_in[0];
  const float* mask      = (const float*)d_in[1];
  const float* centroids = (const float*)d_in[2];
  const float* sd        = (const float*)d_in[3];
  const float* lm        = (const float*)d_in[4];
  float* out = (float*)d_out;

  char* ws = (char*)d_ws;
  float* lp  = (float*)ws;                          // 4 KB
  bf16x8* yh = (bf16x8*)(ws + 4096);                // 256 KB
  bf16x8* ym = (bf16x8*)(ws + 4096 + 262144);       // 256 KB
  bf16x8* yl = (bf16x8*)(ws + 4096 + 2 * 262144);   // 256 KB

  prep<<<65, 256, 0, stream>>>(centroids, lm, yh, ym, yl, lp);
  rmm_main<<<B_R / R_B, 256, 0, stream>>>(samples, mask, sd, lp, yh, ym, yl, out);
}

// Round 6
// 355.269 us; speedup vs baseline: 1.0342x; 1.0342x over previous
//
#include <hip/hip_runtime.h>
#include <math.h>

#define N_C 1024
#define M_F 64
#define B_R 32768
#define R_B 64       // sample rows per block (2 row-halves x 2 m-tiles of 16)
#define NBLK (B_R / R_B)   // 512 blocks = 256 CU x 2 rounds
#define LDX 132      // padded fp32 leading dim for X in LDS

typedef short bf16x8 __attribute__((ext_vector_type(8)));
typedef float f32x4 __attribute__((ext_vector_type(4)));
typedef unsigned int uint4v __attribute__((ext_vector_type(4)));

__device__ __forceinline__ short f2bf(float x) {
  unsigned b = __float_as_uint(x);
  b += 0x7fffu + ((b >> 16) & 1u);   // RTNE (finite inputs only)
  return (short)(b >> 16);
}
__device__ __forceinline__ float bf2f(short h) {
  return __uint_as_float(((unsigned)(unsigned short)h) << 16);
}

// Exact truncation-based 3-way split (h+m+l == x exactly); bit-ops only.
__device__ __forceinline__ void split3(const float* f, bf16x8& h, bf16x8& m, bf16x8& l) {
  uint4v hp, mp, lp;
#pragma unroll
  for (int i = 0; i < 4; ++i) {
    const unsigned b0 = __float_as_uint(f[2 * i]);
    const unsigned b1 = __float_as_uint(f[2 * i + 1]);
    const unsigned h0 = b0 & 0xFFFF0000u, h1 = b1 & 0xFFFF0000u;
    const float r0 = f[2 * i] - __uint_as_float(h0);       // exact
    const float r1 = f[2 * i + 1] - __uint_as_float(h1);   // exact
    hp[i] = (b0 >> 16) | h1;
    const unsigned rb0 = __float_as_uint(r0), rb1 = __float_as_uint(r1);
    const unsigned m0 = rb0 & 0xFFFF0000u, m1 = rb1 & 0xFFFF0000u;
    const float s0 = r0 - __uint_as_float(m0);             // exact
    const float s1 = r1 - __uint_as_float(m1);             // exact
    mp[i] = (rb0 >> 16) | m1;
    lp[i] = (__float_as_uint(s0) >> 16) | (__float_as_uint(s1) & 0xFFFF0000u);
  }
  h = __builtin_bit_cast(bf16x8, hp);
  m = __builtin_bit_cast(bf16x8, mp);
  l = __builtin_bit_cast(bf16x8, lp);
}

// Merged prep: blocks 0..63 build the exact 3-way bf16 split of Y = [C | C^2]
// (MFMA B-frag swizzled); block 64 computes log_softmax(log_marginal).
// Y blob[(s*64 + c)*64 + lane] holds Y[n = c*16+(lane&15)][k = s*32+(lane>>4)*8 ..+7]
__global__ void prep(const float* __restrict__ centroids,
                     const float* __restrict__ lm,
                     bf16x8* __restrict__ yh, bf16x8* __restrict__ ym,
                     bf16x8* __restrict__ yl, float* __restrict__ lp) {
  __shared__ float red[256];
  const int t = threadIdx.x;

  if (blockIdx.x == 64) {
    // ---- log-prior: log_softmax over 1024 entries ----
    float v[4];
    float mx = -INFINITY;
#pragma unroll
    for (int i = 0; i < 4; ++i) { v[i] = lm[i * 256 + t]; mx = fmaxf(mx, v[i]); }
    red[t] = mx;
    __syncthreads();
    for (int s = 128; s > 0; s >>= 1) {
      if (t < s) red[t] = fmaxf(red[t], red[t + s]);
      __syncthreads();
    }
    mx = red[0];
    __syncthreads();
    float sum = 0.f;
#pragma unroll
    for (int i = 0; i < 4; ++i) { v[i] -= mx; sum += expf(v[i]); }
    red[t] = sum;
    __syncthreads();
    for (int s = 128; s > 0; s >>= 1) {
      if (t < s) red[t] += red[t + s];
      __syncthreads();
    }
    const float l = logf(red[0]);
#pragma unroll
    for (int i = 0; i < 4; ++i) lp[i * 256 + t] = v[i] - l;
    return;
  }

  // ---- Y prep ----
  const int tid = blockIdx.x * 256 + t;  // 0..16383
  const int l = tid & 63;
  const int c = (tid >> 6) & 63;
  const int s = tid >> 12;
  const int n = c * 16 + (l & 15);
  const int k0 = s * 32 + (l >> 4) * 8;
  bf16x8 h, mid, lo;
#pragma unroll
  for (int j = 0; j < 8; ++j) {
    const int k = k0 + j;
    float y;
    if (k < 64) {
      y = centroids[n * M_F + k];
    } else {
      const float cc = centroids[n * M_F + (k - 64)];
      y = cc * cc;
    }
    const short hh = f2bf(y);
    const float r1 = y - bf2f(hh);        // exact
    const short mm = f2bf(r1);
    const float r2 = r1 - bf2f(mm);       // exact
    h[j] = hh;
    mid[j] = mm;
    lo[j] = f2bf(r2);                     // exact
  }
  const int blob = (s * 64 + c) * 64 + l;
  yh[blob] = h;
  ym[blob] = mid;
  yl[blob] = lo;
}

// 512 threads = 8 waves = 4 col-strips x 2 row-halves. Wave (w=strip, rh):
// cols w*256..+255, rows rh*32..+31 (2 m-tiles of 16). 512 blocks.
// Rationale: per-block Y read (768 KB) now covers 64 rows instead of 32 ->
// aggregate Y L2 traffic halves (786->393 MB). Each row's softmax still
// combines exactly 4 strip-partials in the same (x+y)+(z+w) order ->
// all outputs bit-identical to the 334us kernel.
__global__ __launch_bounds__(512, 2) void rmm_main(
    const float* __restrict__ samples, const float* __restrict__ mask,
    const float* __restrict__ sd, const float* __restrict__ lp_g,
    const bf16x8* __restrict__ yh_g, const bf16x8* __restrict__ ym_g,
    const bf16x8* __restrict__ yl_g, float* __restrict__ out) {
  __shared__ float xs[R_B * LDX];   // X fp32 [row][k]: k<64 -> -2uA, k>=64 -> u
  __shared__ float lp_s[N_C];
  __shared__ float ad_s[R_B];
  __shared__ float red_s[R_B * 4];

  const int t = threadIdx.x;
  const int b0 = blockIdx.x * R_B;
  const int wid = t >> 6;           // 0..7
  const int w = wid & 3;            // col strip
  const int rh = wid >> 2;          // row half
  const int l = t & 63;
  const int m = l & 15;
  const int q = l >> 4;

  if (t < 256) *(float4*)(lp_s + (t << 2)) = *(const float4*)(lp_g + (t << 2));

  // Prefill B pairs 0,1 (tiles 0..3 of s=0): latency hides under X-build.
  // (Both row-half waves of a strip read identical addresses -> L1 hits.)
  const size_t base0 = (size_t)(w * 16) * 64 + l;
  bf16x8 Bh[2][2], Bm[2][2], Bl[2][2];   // [pair-slot][elem]
#pragma unroll
  for (int p = 0; p < 2; ++p)
#pragma unroll
    for (int e = 0; e < 2; ++e) {
      Bh[p][e] = yh_g[base0 + (p * 2 + e) * 64];
      Bm[p][e] = ym_g[base0 + (p * 2 + e) * 64];
      Bl[p][e] = yl_g[base0 + (p * 2 + e) * 64];
    }

  // ---- build X rows, A_d: 512 thr = 64 rows x 8 lanes x 8 features ----
  // (identical per-row lane decomposition/op order -> xs/ad bit-identical)
  {
    const int r = t >> 3;             // 0..63
    const int j8 = (t & 7) << 3;
    const float* sp = samples + (size_t)(b0 + r) * M_F + j8;
    const float* mp = mask + (size_t)(b0 + r) * M_F + j8;
    float sa[8], ma[8], da[8];
    *(float4*)&sa[0] = *(const float4*)sp;
    *(float4*)&sa[4] = *(const float4*)(sp + 4);
    *(float4*)&ma[0] = *(const float4*)mp;
    *(float4*)&ma[4] = *(const float4*)(mp + 4);
    *(float4*)&da[0] = *(const float4*)(sd + j8);
    *(float4*)&da[4] = *(const float4*)(sd + j8 + 4);
    float ad = 0.f;
#pragma unroll
    for (int k = 0; k < 8; ++k) {
      const float mm = ma[k] / da[k];
      const float uu = mm * mm;
      const float mA = mm * sa[k];
      ad = fmaf(mA, mA, ad);
      xs[r * LDX + j8 + k] = -2.0f * (uu * sa[k]);
      xs[r * LDX + 64 + j8 + k] = uu;
    }
#pragma unroll
    for (int off = 1; off < 8; off <<= 1) ad += __shfl_xor(ad, off, 64);
    if ((t & 7) == 0) ad_s[r] = ad;
  }

  f32x4 acc[2][16];
#pragma unroll
  for (int mt = 0; mt < 2; ++mt)
#pragma unroll
    for (int c = 0; c < 16; ++c) acc[mt][c] = (f32x4){0.f, 0.f, 0.f, 0.f};

  __syncthreads();

  // split order per accumulator (small -> large); 0=h,1=m,2=l
  const int sx[8] = {1, 2, 0, 1, 2, 0, 1, 0};
  const int sy[8] = {2, 1, 2, 1, 0, 1, 0, 0};

  // ---- K loop: 4 steps of K=32; pair-granular double-buffered prefetch,
  //      depth 2 pairs (4 tiles), carried across s ----
#pragma unroll 1
  for (int s = 0; s < 4; ++s) {
    const size_t sbase = (size_t)(s * 64 + w * 16) * 64 + l;
    const bf16x8* yh = yh_g + sbase;
    const bf16x8* ym = ym_g + sbase;
    const bf16x8* yl = yl_g + sbase;

    bf16x8 A[3][2];
#pragma unroll
    for (int mt = 0; mt < 2; ++mt) {
      const float* xp = &xs[(rh * 32 + mt * 16 + m) * LDX + s * 32 + q * 8];
      float av[8];
      *(float4*)&av[0] = *(const float4*)xp;
      *(float4*)&av[4] = *(const float4*)(xp + 4);
      split3(av, A[0][mt], A[1][mt], A[2][mt]);
    }

#pragma unroll
    for (int cp = 0; cp < 8; ++cp) {
      const int buf = cp & 1;
      // current pair's fragments (copy before overwrite by prefetch)
      const bf16x8 bh0 = Bh[buf][0], bm0 = Bm[buf][0], bl0 = Bl[buf][0];
      const bf16x8 bh1 = Bh[buf][1], bm1 = Bm[buf][1], bl1 = Bl[buf][1];
      // prefetch pair cp+2 into this slot (pf>=16 -> next K-step's tiles)
      const int pf0 = 2 * cp + 4;
      if (s < 3 || pf0 + 1 < 16) {
        const int o0 = (pf0 < 16) ? pf0 * 64 : 4096 + (pf0 - 16) * 64;
        const int o1 = (pf0 + 1 < 16) ? (pf0 + 1) * 64 : 4096 + (pf0 - 15) * 64;
        Bh[buf][0] = yh[o0]; Bm[buf][0] = ym[o0]; Bl[buf][0] = yl[o0];
        Bh[buf][1] = yh[o1]; Bm[buf][1] = ym[o1]; Bl[buf][1] = yl[o1];
      }
      const int c0 = 2 * cp, c1 = 2 * cp + 1;
#pragma unroll
      for (int sp = 0; sp < 8; ++sp) {
        const bf16x8 b0 = (sy[sp] == 0) ? bh0 : ((sy[sp] == 1) ? bm0 : bl0);
        const bf16x8 b1 = (sy[sp] == 0) ? bh1 : ((sy[sp] == 1) ? bm1 : bl1);
        // 4 independent chains between dependent uses of the same acc
#pragma unroll
        for (int mt = 0; mt < 2; ++mt)
          acc[mt][c0] = __builtin_amdgcn_mfma_f32_16x16x32_bf16(
              A[sx[sp]][mt], b0, acc[mt][c0], 0, 0, 0);
#pragma unroll
        for (int mt = 0; mt < 2; ++mt)
          acc[mt][c1] = __builtin_amdgcn_mfma_f32_16x16x32_bf16(
              A[sx[sp]][mt], b1, acc[mt][c1], 0, 0, 0);
      }
    }
  }

  // ---- epilogue: C/D row = rh*32 + mt*16 + q*4+g, col = w*256 + c*16 + m ----
  float adv[2][4];
#pragma unroll
  for (int mt = 0; mt < 2; ++mt)
#pragma unroll
    for (int g = 0; g < 4; ++g) adv[mt][g] = ad_s[rh * 32 + mt * 16 + q * 4 + g];
  float lpv[16];
#pragma unroll
  for (int c = 0; c < 16; ++c) lpv[c] = lp_s[w * 256 + c * 16 + m];

#pragma unroll
  for (int mt = 0; mt < 2; ++mt)
#pragma unroll
    for (int c = 0; c < 16; ++c)
#pragma unroll
      for (int g = 0; g < 4; ++g) {
        const float dist = fmaxf(adv[mt][g] + acc[mt][c][g], 0.0f);
        acc[mt][c][g] = lpv[c] - 0.5f * dist;
      }

  float mx[2][4];
#pragma unroll
  for (int mt = 0; mt < 2; ++mt)
#pragma unroll
    for (int g = 0; g < 4; ++g) {
      float v = acc[mt][0][g];
#pragma unroll
      for (int c = 1; c < 16; ++c) v = fmaxf(v, acc[mt][c][g]);
#pragma unroll
      for (int off = 1; off < 16; off <<= 1) v = fmaxf(v, __shfl_xor(v, off, 64));
      mx[mt][g] = v;
    }
  if (m == 0) {
#pragma unroll
    for (int mt = 0; mt < 2; ++mt)
#pragma unroll
      for (int g = 0; g < 4; ++g)
        red_s[(rh * 32 + mt * 16 + q * 4 + g) * 4 + w] = mx[mt][g];
  }
  __syncthreads();
#pragma unroll
  for (int mt = 0; mt < 2; ++mt)
#pragma unroll
    for (int g = 0; g < 4; ++g) {
      const float4 rv = *(const float4*)(&red_s[(rh * 32 + mt * 16 + q * 4 + g) * 4]);
      mx[mt][g] = fmaxf(fmaxf(rv.x, rv.y), fmaxf(rv.z, rv.w));
    }
  __syncthreads();

  float sm[2][4];
#pragma unroll
  for (int mt = 0; mt < 2; ++mt)
#pragma unroll
    for (int g = 0; g < 4; ++g) {
      float ssum = 0.f;
#pragma unroll
      for (int c = 0; c < 16; ++c) {
        const float e = __expf(acc[mt][c][g] - mx[mt][g]);
        acc[mt][c][g] = e;
        ssum += e;
      }
#pragma unroll
      for (int off = 1; off < 16; off <<= 1) ssum += __shfl_xor(ssum, off, 64);
      sm[mt][g] = ssum;
    }
  if (m == 0) {
#pragma unroll
    for (int mt = 0; mt < 2; ++mt)
#pragma unroll
      for (int g = 0; g < 4; ++g)
        red_s[(rh * 32 + mt * 16 + q * 4 + g) * 4 + w] = sm[mt][g];
  }
  __syncthreads();
#pragma unroll
  for (int mt = 0; mt < 2; ++mt)
#pragma unroll
    for (int g = 0; g < 4; ++g) {
      const float4 rv = *(const float4*)(&red_s[(rh * 32 + mt * 16 + q * 4 + g) * 4]);
      sm[mt][g] = (rv.x + rv.y) + (rv.z + rv.w);
    }
  __syncthreads();

  float thr[2][4], qs[2][4];
#pragma unroll
  for (int mt = 0; mt < 2; ++mt)
#pragma unroll
    for (int g = 0; g < 4; ++g) {
      const float S1 = sm[mt][g];
      thr[mt][g] = 0.05f * (1.0f / S1);
      float s2 = 0.f;
#pragma unroll
      for (int c = 0; c < 16; ++c) {
        const float p = acc[mt][c][g] / S1;   // IEEE div, matches np decision band
        acc[mt][c][g] = p;
        s2 += (p > thr[mt][g]) ? p : 0.0f;
      }
#pragma unroll
      for (int off = 1; off < 16; off <<= 1) s2 += __shfl_xor(s2, off, 64);
      qs[mt][g] = s2;
    }
  if (m == 0) {
#pragma unroll
    for (int mt = 0; mt < 2; ++mt)
#pragma unroll
      for (int g = 0; g < 4; ++g)
        red_s[(rh * 32 + mt * 16 + q * 4 + g) * 4 + w] = qs[mt][g];
  }
  __syncthreads();
#pragma unroll
  for (int mt = 0; mt < 2; ++mt)
#pragma unroll
    for (int g = 0; g < 4; ++g) {
      const float4 rv = *(const float4*)(&red_s[(rh * 32 + mt * 16 + q * 4 + g) * 4]);
      qs[mt][g] = (rv.x + rv.y) + (rv.z + rv.w);
    }

  const size_t colbase = (size_t)(w * 256 + m);
#pragma unroll
  for (int mt = 0; mt < 2; ++mt)
#pragma unroll
    for (int g = 0; g < 4; ++g) {
      const float rq = 1.0f / qs[mt][g];
      float* orow = out + (size_t)(b0 + rh * 32 + mt * 16 + q * 4 + g) * N_C + colbase;
      float* lrow = orow + (size_t)B_R * N_C;
#pragma unroll
      for (int c = 0; c < 16; ++c) {
        const float p = acc[mt][c][g];
        const float pf = (p > thr[mt][g]) ? (p * rq) : 0.0f;
        orow[c * 16] = pf;
        lrow[c * 16] = __logf(pf + 1e-20f);
      }
    }
}

extern "C" void kernel_launch(void* const* d_in, const int* in_sizes, int n_in,
                              void* d_out, int out_size, void* d_ws, size_t ws_size,
                              hipStream_t stream) {
  const float* samples   = (const float*)d_in[0];
  const float* mask      = (const float*)d_in[1];
  const float* centroids = (const float*)d_in[2];
  const float* sd        = (const float*)d_in[3];
  const float* lm        = (const float*)d_in[4];
  float* out = (float*)d_out;

  char* ws = (char*)d_ws;
  float* lp  = (float*)ws;                          // 4 KB
  bf16x8* yh = (bf16x8*)(ws + 4096);                // 256 KB
  bf16x8* ym = (bf16x8*)(ws + 4096 + 262144);       // 256 KB
  bf16x8* yl = (bf16x8*)(ws + 4096 + 2 * 262144);   // 256 KB

  prep<<<65, 256, 0, stream>>>(centroids, lm, yh, ym, yl, lp);
  rmm_main<<<NBLK, 512, 0, stream>>>(samples, mask, sd, lp, yh, ym, yl, out);
}

// Round 7
// 334.422 us; speedup vs baseline: 1.0987x; 1.0623x over previous
//
#include <hip/hip_runtime.h>
#include <math.h>

#define N_C 1024
#define M_F 64
#define B_R 32768
#define R_B 32       // sample rows per block (2 m-tiles of 16)
#define LDX 132      // padded fp32 leading dim for X in LDS

typedef short bf16x8 __attribute__((ext_vector_type(8)));
typedef float f32x4 __attribute__((ext_vector_type(4)));
typedef unsigned int uint4v __attribute__((ext_vector_type(4)));

__device__ __forceinline__ short f2bf(float x) {
  unsigned b = __float_as_uint(x);
  b += 0x7fffu + ((b >> 16) & 1u);   // RTNE (finite inputs only)
  return (short)(b >> 16);
}
__device__ __forceinline__ float bf2f(short h) {
  return __uint_as_float(((unsigned)(unsigned short)h) << 16);
}

// Exact truncation-based 3-way split (h+m+l == x exactly); bit-ops only.
__device__ __forceinline__ void split3(const float* f, bf16x8& h, bf16x8& m, bf16x8& l) {
  uint4v hp, mp, lp;
#pragma unroll
  for (int i = 0; i < 4; ++i) {
    const unsigned b0 = __float_as_uint(f[2 * i]);
    const unsigned b1 = __float_as_uint(f[2 * i + 1]);
    const unsigned h0 = b0 & 0xFFFF0000u, h1 = b1 & 0xFFFF0000u;
    const float r0 = f[2 * i] - __uint_as_float(h0);       // exact
    const float r1 = f[2 * i + 1] - __uint_as_float(h1);   // exact
    hp[i] = (b0 >> 16) | h1;
    const unsigned rb0 = __float_as_uint(r0), rb1 = __float_as_uint(r1);
    const unsigned m0 = rb0 & 0xFFFF0000u, m1 = rb1 & 0xFFFF0000u;
    const float s0 = r0 - __uint_as_float(m0);             // exact
    const float s1 = r1 - __uint_as_float(m1);             // exact
    mp[i] = (rb0 >> 16) | m1;
    lp[i] = (__float_as_uint(s0) >> 16) | (__float_as_uint(s1) & 0xFFFF0000u);
  }
  h = __builtin_bit_cast(bf16x8, hp);
  m = __builtin_bit_cast(bf16x8, mp);
  l = __builtin_bit_cast(bf16x8, lp);
}

__global__ void logprior_kernel(const float* __restrict__ lm, float* __restrict__ lp) {
  __shared__ float red[256];
  const int t = threadIdx.x;
  float v[4];
  float mx = -INFINITY;
#pragma unroll
  for (int i = 0; i < 4; ++i) { v[i] = lm[i * 256 + t]; mx = fmaxf(mx, v[i]); }
  red[t] = mx;
  __syncthreads();
  for (int s = 128; s > 0; s >>= 1) {
    if (t < s) red[t] = fmaxf(red[t], red[t + s]);
    __syncthreads();
  }
  mx = red[0];
  __syncthreads();
  float sum = 0.f;
#pragma unroll
  for (int i = 0; i < 4; ++i) { v[i] -= mx; sum += expf(v[i]); }
  red[t] = sum;
  __syncthreads();
  for (int s = 128; s > 0; s >>= 1) {
    if (t < s) red[t] += red[t + s];
    __syncthreads();
  }
  const float l = logf(red[0]);
#pragma unroll
  for (int i = 0; i < 4; ++i) lp[i * 256 + t] = v[i] - l;
}

// Exact 3-way bf16 split of Y = [C | C^2], MFMA B-frag swizzled:
// blob[(s*64 + c)*64 + lane] holds Y[n = c*16+(lane&15)][k = s*32+(lane>>4)*8 ..+7]
__global__ void prep_y(const float* __restrict__ centroids,
                       bf16x8* __restrict__ yh, bf16x8* __restrict__ ym,
                       bf16x8* __restrict__ yl) {
  const int tid = blockIdx.x * 256 + threadIdx.x;  // 0..16383
  const int l = tid & 63;
  const int c = (tid >> 6) & 63;
  const int s = tid >> 12;
  const int n = c * 16 + (l & 15);
  const int k0 = s * 32 + (l >> 4) * 8;
  bf16x8 h, mid, lo;
#pragma unroll
  for (int j = 0; j < 8; ++j) {
    const int k = k0 + j;
    float y;
    if (k < 64) {
      y = centroids[n * M_F + k];
    } else {
      const float cc = centroids[n * M_F + (k - 64)];
      y = cc * cc;
    }
    const short hh = f2bf(y);
    const float r1 = y - bf2f(hh);        // exact
    const short mm = f2bf(r1);
    const float r2 = r1 - bf2f(mm);       // exact
    h[j] = hh;
    mid[j] = mm;
    lo[j] = f2bf(r2);                     // exact
  }
  const int blob = (s * 64 + c) * 64 + l;
  yh[blob] = h;
  ym[blob] = mid;
  yl[blob] = lo;
}

// 256 threads = 4 waves. Wave w: c-tiles w*16..w*16+15 (cols w*256..+255),
// 2 m-tiles (rows 0-15, 16-31). 1024 blocks.
__global__ __launch_bounds__(256, 2) void rmm_main(
    const float* __restrict__ samples, const float* __restrict__ mask,
    const float* __restrict__ sd, const float* __restrict__ lp_g,
    const bf16x8* __restrict__ yh_g, const bf16x8* __restrict__ ym_g,
    const bf16x8* __restrict__ yl_g, float* __restrict__ out) {
  __shared__ float xs[R_B * LDX];   // X fp32 [row][k]: k<64 -> -2uA, k>=64 -> u
  __shared__ float lp_s[N_C];
  __shared__ float ad_s[R_B];
  __shared__ float red_s[R_B * 4];

  const int t = threadIdx.x;
  const int b0 = blockIdx.x * R_B;
  const int w = t >> 6;
  const int l = t & 63;
  const int m = l & 15;
  const int q = l >> 4;

  *(float4*)(lp_s + (t << 2)) = *(const float4*)(lp_g + (t << 2));

  // ---- build X rows, A_d: 256 thr = 32 rows x 8 lanes x 8 features ----
  {
    const int r = t >> 3;             // 0..31
    const int j8 = (t & 7) << 3;
    const float* sp = samples + (size_t)(b0 + r) * M_F + j8;
    const float* mp = mask + (size_t)(b0 + r) * M_F + j8;
    float sa[8], ma[8], da[8];
    *(float4*)&sa[0] = *(const float4*)sp;
    *(float4*)&sa[4] = *(const float4*)(sp + 4);
    *(float4*)&ma[0] = *(const float4*)mp;
    *(float4*)&ma[4] = *(const float4*)(mp + 4);
    *(float4*)&da[0] = *(const float4*)(sd + j8);
    *(float4*)&da[4] = *(const float4*)(sd + j8 + 4);
    float ad = 0.f;
#pragma unroll
    for (int k = 0; k < 8; ++k) {
      const float mm = ma[k] / da[k];
      const float uu = mm * mm;
      const float mA = mm * sa[k];
      ad = fmaf(mA, mA, ad);
      xs[r * LDX + j8 + k] = -2.0f * (uu * sa[k]);
      xs[r * LDX + 64 + j8 + k] = uu;
    }
#pragma unroll
    for (int off = 1; off < 8; off <<= 1) ad += __shfl_xor(ad, off, 64);
    if ((t & 7) == 0) ad_s[r] = ad;
  }

  f32x4 acc[2][16];
#pragma unroll
  for (int mt = 0; mt < 2; ++mt)
#pragma unroll
    for (int c = 0; c < 16; ++c) acc[mt][c] = (f32x4){0.f, 0.f, 0.f, 0.f};

  __syncthreads();

  // split order per accumulator (small -> large); 0=h,1=m,2=l
  const int sx[8] = {1, 2, 0, 1, 2, 0, 1, 0};
  const int sy[8] = {2, 1, 2, 1, 0, 1, 0, 0};

  // ---- K loop: 4 steps of K=32 ----
#pragma unroll 1
  for (int s = 0; s < 4; ++s) {
    const size_t sbase = (size_t)(s * 64 + w * 16) * 64 + l;
    const bf16x8* yh = yh_g + sbase;
    const bf16x8* ym = ym_g + sbase;
    const bf16x8* yl = yl_g + sbase;

    // issue first B loads, then build A frags (covers L2 latency)
    bf16x8 Bh[2], Bm[2], Bl[2];
#pragma unroll
    for (int p = 0; p < 2; ++p) {
      Bh[p] = yh[p * 64];
      Bm[p] = ym[p * 64];
      Bl[p] = yl[p * 64];
    }

    bf16x8 A[3][2];
#pragma unroll
    for (int mt = 0; mt < 2; ++mt) {
      const float* xp = &xs[(mt * 16 + m) * LDX + s * 32 + q * 8];
      float av[8];
      *(float4*)&av[0] = *(const float4*)xp;
      *(float4*)&av[4] = *(const float4*)(xp + 4);
      split3(av, A[0][mt], A[1][mt], A[2][mt]);
    }

#pragma unroll
    for (int c = 0; c < 16; ++c) {
      const int cur = c & 1;
      const bf16x8 bh = Bh[cur], bm = Bm[cur], bl = Bl[cur];
      if (c < 14) {
        Bh[cur] = yh[(c + 2) * 64];
        Bm[cur] = ym[(c + 2) * 64];
        Bl[cur] = yl[(c + 2) * 64];
      }
#pragma unroll
      for (int sp = 0; sp < 8; ++sp) {
        const bf16x8 bb = (sy[sp] == 0) ? bh : ((sy[sp] == 1) ? bm : bl);
#pragma unroll
        for (int mt = 0; mt < 2; ++mt)
          acc[mt][c] = __builtin_amdgcn_mfma_f32_16x16x32_bf16(
              A[sx[sp]][mt], bb, acc[mt][c], 0, 0, 0);
      }
    }
  }

  // ---- epilogue: C/D row = mt*16 + q*4+g, col = w*256 + c*16 + m ----
  float adv[2][4];
#pragma unroll
  for (int mt = 0; mt < 2; ++mt)
#pragma unroll
    for (int g = 0; g < 4; ++g) adv[mt][g] = ad_s[mt * 16 + q * 4 + g];
  float lpv[16];
#pragma unroll
  for (int c = 0; c < 16; ++c) lpv[c] = lp_s[w * 256 + c * 16 + m];

#pragma unroll
  for (int mt = 0; mt < 2; ++mt)
#pragma unroll
    for (int c = 0; c < 16; ++c)
#pragma unroll
      for (int g = 0; g < 4; ++g) {
        const float dist = fmaxf(adv[mt][g] + acc[mt][c][g], 0.0f);
        acc[mt][c][g] = lpv[c] - 0.5f * dist;
      }

  float mx[2][4];
#pragma unroll
  for (int mt = 0; mt < 2; ++mt)
#pragma unroll
    for (int g = 0; g < 4; ++g) {
      float v = acc[mt][0][g];
#pragma unroll
      for (int c = 1; c < 16; ++c) v = fmaxf(v, acc[mt][c][g]);
#pragma unroll
      for (int off = 1; off < 16; off <<= 1) v = fmaxf(v, __shfl_xor(v, off, 64));
      mx[mt][g] = v;
    }
  if (m == 0) {
#pragma unroll
    for (int mt = 0; mt < 2; ++mt)
#pragma unroll
      for (int g = 0; g < 4; ++g) red_s[(mt * 16 + q * 4 + g) * 4 + w] = mx[mt][g];
  }
  __syncthreads();
#pragma unroll
  for (int mt = 0; mt < 2; ++mt)
#pragma unroll
    for (int g = 0; g < 4; ++g) {
      const float4 rv = *(const float4*)(&red_s[(mt * 16 + q * 4 + g) * 4]);
      mx[mt][g] = fmaxf(fmaxf(rv.x, rv.y), fmaxf(rv.z, rv.w));
    }
  __syncthreads();

  float sm[2][4];
#pragma unroll
  for (int mt = 0; mt < 2; ++mt)
#pragma unroll
    for (int g = 0; g < 4; ++g) {
      float ssum = 0.f;
#pragma unroll
      for (int c = 0; c < 16; ++c) {
        const float e = __expf(acc[mt][c][g] - mx[mt][g]);
        acc[mt][c][g] = e;
        ssum += e;
      }
#pragma unroll
      for (int off = 1; off < 16; off <<= 1) ssum += __shfl_xor(ssum, off, 64);
      sm[mt][g] = ssum;
    }
  if (m == 0) {
#pragma unroll
    for (int mt = 0; mt < 2; ++mt)
#pragma unroll
      for (int g = 0; g < 4; ++g) red_s[(mt * 16 + q * 4 + g) * 4 + w] = sm[mt][g];
  }
  __syncthreads();
#pragma unroll
  for (int mt = 0; mt < 2; ++mt)
#pragma unroll
    for (int g = 0; g < 4; ++g) {
      const float4 rv = *(const float4*)(&red_s[(mt * 16 + q * 4 + g) * 4]);
      sm[mt][g] = (rv.x + rv.y) + (rv.z + rv.w);
    }
  __syncthreads();

  float thr[2][4], qs[2][4];
#pragma unroll
  for (int mt = 0; mt < 2; ++mt)
#pragma unroll
    for (int g = 0; g < 4; ++g) {
      const float S1 = sm[mt][g];
      thr[mt][g] = 0.05f * (1.0f / S1);
      float s2 = 0.f;
#pragma unroll
      for (int c = 0; c < 16; ++c) {
        const float p = acc[mt][c][g] / S1;   // IEEE div, matches np decision band
        acc[mt][c][g] = p;
        s2 += (p > thr[mt][g]) ? p : 0.0f;
      }
#pragma unroll
      for (int off = 1; off < 16; off <<= 1) s2 += __shfl_xor(s2, off, 64);
      qs[mt][g] = s2;
    }
  if (m == 0) {
#pragma unroll
    for (int mt = 0; mt < 2; ++mt)
#pragma unroll
      for (int g = 0; g < 4; ++g) red_s[(mt * 16 + q * 4 + g) * 4 + w] = qs[mt][g];
  }
  __syncthreads();
#pragma unroll
  for (int mt = 0; mt < 2; ++mt)
#pragma unroll
    for (int g = 0; g < 4; ++g) {
      const float4 rv = *(const float4*)(&red_s[(mt * 16 + q * 4 + g) * 4]);
      qs[mt][g] = (rv.x + rv.y) + (rv.z + rv.w);
    }

  const size_t colbase = (size_t)(w * 256 + m);
#pragma unroll
  for (int mt = 0; mt < 2; ++mt)
#pragma unroll
    for (int g = 0; g < 4; ++g) {
      const float rq = 1.0f / qs[mt][g];
      float* orow = out + (size_t)(b0 + mt * 16 + q * 4 + g) * N_C + colbase;
      float* lrow = orow + (size_t)B_R * N_C;
#pragma unroll
      for (int c = 0; c < 16; ++c) {
        const float p = acc[mt][c][g];
        const float pf = (p > thr[mt][g]) ? (p * rq) : 0.0f;
        orow[c * 16] = pf;
        lrow[c * 16] = __logf(pf + 1e-20f);
      }
    }
}

extern "C" void kernel_launch(void* const* d_in, const int* in_sizes, int n_in,
                              void* d_out, int out_size, void* d_ws, size_t ws_size,
                              hipStream_t stream) {
  const float* samples   = (const float*)d_in[0];
  const float* mask      = (const float*)d_in[1];
  const float* centroids = (const float*)d_in[2];
  const float* sd        = (const float*)d_in[3];
  const float* lm        = (const float*)d_in[4];
  float* out = (float*)d_out;

  char* ws = (char*)d_ws;
  float* lp  = (float*)ws;                          // 4 KB
  bf16x8* yh = (bf16x8*)(ws + 4096);                // 256 KB
  bf16x8* ym = (bf16x8*)(ws + 4096 + 262144);       // 256 KB
  bf16x8* yl = (bf16x8*)(ws + 4096 + 2 * 262144);   // 256 KB

  logprior_kernel<<<1, 256, 0, stream>>>(lm, lp);
  prep_y<<<64, 256, 0, stream>>>(centroids, yh, ym, yl);
  rmm_main<<<B_R / R_B, 256, 0, stream>>>(samples, mask, sd, lp, yh, ym, yl, out);
}